// Round 4
// baseline (1741.796 us; speedup 1.0000x reference)
//
#include <hip/hip_runtime.h>
#include <math.h>

#define BUCKET_SHIFT 8            // 256 nodes per bucket
#define BUCKET_MASK 255
#define MAXBUCK 640               // supports N <= 163840
#define TILE 8192

__device__ inline float bf_lo(unsigned u) { return __uint_as_float(u << 16); }
__device__ inline float bf_hi(unsigned u) { return __uint_as_float(u & 0xffff0000u); }
__device__ inline unsigned short f2bf(float f) {   // round-to-nearest-even
  unsigned u = __float_as_uint(f);
  return (unsigned short)((u + 0x7fffu + ((u >> 16) & 1u)) >> 16);
}

// ---------------- utility ----------------
__global__ void zero_u32(unsigned int* __restrict__ p, int n) {
  int i = blockIdx.x * blockDim.x + threadIdx.x;
  if (i < n) p[i] = 0u;
}

// ---------------- bucketed CSR build ----------------
__global__ __launch_bounds__(256) void bucket_count(const int* __restrict__ dst,
                                                    int* __restrict__ bcnt, int e, int nbuck) {
  __shared__ int lc[MAXBUCK];
  for (int i = threadIdx.x; i < nbuck; i += 256) lc[i] = 0;
  __syncthreads();
  for (int i = blockIdx.x * blockDim.x + threadIdx.x; i < e; i += gridDim.x * blockDim.x)
    atomicAdd(&lc[dst[i] >> BUCKET_SHIFT], 1);
  __syncthreads();
  for (int i = threadIdx.x; i < nbuck; i += 256)
    if (lc[i]) atomicAdd(&bcnt[i], lc[i]);
}

__global__ __launch_bounds__(1024) void bucket_scan(const int* __restrict__ bcnt,
                                                    int* __restrict__ bbase,
                                                    int* __restrict__ bcur, int nbuck) {
  __shared__ int s[1024];
  int t = threadIdx.x;
  int v = (t < nbuck) ? bcnt[t] : 0;
  s[t] = v;
  __syncthreads();
  for (int off = 1; off < 1024; off <<= 1) {
    int u = (t >= off) ? s[t - off] : 0;
    __syncthreads();
    s[t] += u;
    __syncthreads();
  }
  int excl = s[t] - v;
  if (t < nbuck) {
    bbase[t] = excl;
    bcur[t] = excl;
  } else if (t == nbuck) {
    bbase[t] = excl;               // == total E
  }
}

__global__ __launch_bounds__(256) void bucket_scatter(const int* __restrict__ src,
                                                      const int* __restrict__ dst,
                                                      int* __restrict__ bcur,
                                                      int2* __restrict__ bucketed,
                                                      int e, int nbuck) {
  __shared__ int lcnt[MAXBUCK], loff[MAXBUCK], lcur[MAXBUCK], gbase[MAXBUCK];
  __shared__ int stmp[256];
  __shared__ int scarry;
  int t = threadIdx.x;
  int tile0 = blockIdx.x * TILE;
  int tn = min(TILE, e - tile0);
  __shared__ int2 lout[TILE];

  for (int i = t; i < nbuck; i += 256) lcnt[i] = 0;
  if (t == 0) scarry = 0;
  __syncthreads();
  for (int i = t; i < tn; i += 256)
    atomicAdd(&lcnt[dst[tile0 + i] >> BUCKET_SHIFT], 1);
  __syncthreads();
  for (int c0 = 0; c0 < nbuck; c0 += 256) {
    int idx = c0 + t;
    int v = (idx < nbuck) ? lcnt[idx] : 0;
    stmp[t] = v;
    __syncthreads();
    for (int off = 1; off < 256; off <<= 1) {
      int u = (t >= off) ? stmp[t - off] : 0;
      __syncthreads();
      stmp[t] += u;
      __syncthreads();
    }
    int excl = stmp[t] - v + scarry;
    if (idx < nbuck) { loff[idx] = excl; lcur[idx] = excl; }
    __syncthreads();
    if (t == 255) scarry += stmp[255];
    __syncthreads();
  }
  for (int i = t; i < tn; i += 256) {
    int d = dst[tile0 + i];
    int s = src[tile0 + i];
    int b = d >> BUCKET_SHIFT;
    int pos = atomicAdd(&lcur[b], 1);
    lout[pos] = make_int2(s, d);
  }
  __syncthreads();
  for (int i = t; i < nbuck; i += 256)
    if (lcnt[i] > 0) gbase[i] = atomicAdd(&bcur[i], lcnt[i]);
  __syncthreads();
  for (int j = t; j < tn; j += 256) {
    int2 v = lout[j];
    int b = v.y >> BUCKET_SHIFT;
    bucketed[gbase[b] + (j - loff[b])] = v;
  }
}

__global__ __launch_bounds__(256) void bucket_to_csr(const int2* __restrict__ bucketed,
                                                     const int* __restrict__ bbase,
                                                     int* __restrict__ rp,
                                                     float* __restrict__ dinv,
                                                     int* __restrict__ csr,
                                                     int n, int e, int nbuck) {
  __shared__ int lcnt[256], lrp[256];
  int b = blockIdx.x, t = threadIdx.x;
  int n0 = b << BUCKET_SHIFT;
  int base = bbase[b];
  int cnt_e = bbase[b + 1] - base;
  lcnt[t] = 0;
  __syncthreads();
  for (int i = t; i < cnt_e; i += 256)
    atomicAdd(&lcnt[bucketed[base + i].y & BUCKET_MASK], 1);
  __syncthreads();
  int v = lcnt[t];
  lrp[t] = v;
  __syncthreads();
  for (int off = 1; off < 256; off <<= 1) {
    int u = (t >= off) ? lrp[t - off] : 0;
    __syncthreads();
    lrp[t] += u;
    __syncthreads();
  }
  int excl = lrp[t] - v;
  int node = n0 + t;
  if (node < n) {
    rp[node] = base + excl;
    dinv[node] = rsqrtf((float)v + 1.0f);   // +1 self loop
  }
  if (b == nbuck - 1 && t == 0) rp[n] = e;
  lrp[t] = excl;
  lcnt[t] = 0;
  __syncthreads();
  for (int i = t; i < cnt_e; i += 256) {
    int2 ed = bucketed[base + i];
    int li = ed.y & BUCKET_MASK;
    int pos = atomicAdd(&lcnt[li], 1);
    csr[base + lrp[li] + pos] = ed.x;
  }
}

// ---------------- graph boundaries from sorted batch (no atomics) ----------------
__global__ void graph_bounds(const int* __restrict__ batch, int* __restrict__ gstart,
                             int n, int g) {
  int i = blockIdx.x * blockDim.x + threadIdx.x;
  if (i >= n) return;
  int b = batch[i];
  int bp = (i == 0) ? -1 : batch[i - 1];
  for (int k = bp + 1; k <= b; ++k) gstart[k] = i;
  if (i == n - 1)
    for (int k = b + 1; k <= g; ++k) gstart[k] = n;
}

// ---------------- layer 1: aggregate raw x (F=3), then linear ----------------
__global__ void agg_f3(const float* __restrict__ x, const int* __restrict__ rp,
                       const int* __restrict__ csr, const float* __restrict__ dinv,
                       float* __restrict__ out, int n) {
  int i = blockIdx.x * blockDim.x + threadIdx.x;
  if (i >= n) return;
  float dd = dinv[i];
  float w0 = dd * dd;
  float a0 = x[3 * (size_t)i + 0] * w0;
  float a1 = x[3 * (size_t)i + 1] * w0;
  float a2 = x[3 * (size_t)i + 2] * w0;
  int e0 = rp[i], e1 = rp[i + 1];
  for (int e = e0; e < e1; ++e) {
    int s = csr[e];
    float w = dinv[s] * dd;
    a0 += x[3 * (size_t)s + 0] * w;
    a1 += x[3 * (size_t)s + 1] * w;
    a2 += x[3 * (size_t)s + 2] * w;
  }
  out[4 * (size_t)i + 0] = a0;
  out[4 * (size_t)i + 1] = a1;
  out[4 * (size_t)i + 2] = a2;
}

__global__ void lin_f3(const float* __restrict__ ag, const float* __restrict__ W1,
                       const float* __restrict__ b1, float* __restrict__ out, int n) {
  int idx = blockIdx.x * blockDim.x + threadIdx.x;
  if (idx >= n * 128) return;
  int node = idx >> 7, f = idx & 127;
  float a = b1[f]
          + ag[4 * (size_t)node + 0] * W1[f]
          + ag[4 * (size_t)node + 1] * W1[128 + f]
          + ag[4 * (size_t)node + 2] * W1[256 + f];
  out[idx] = a;
}

// ---------------- batch norm ----------------
__global__ void bn_stats(const float* __restrict__ x, float* __restrict__ stats, int n) {
  int t = threadIdx.x;
  int f = t & 127, half = t >> 7;
  float s = 0.f, q = 0.f;
  for (int r = blockIdx.x * 2 + half; r < n; r += gridDim.x * 2) {
    float v = x[(size_t)r * 128 + f];
    s += v;
    q += v * v;
  }
  __shared__ float ls[256], lq[256];
  ls[t] = s; lq[t] = q;
  __syncthreads();
  if (half == 0) {
    atomicAdd(&stats[f], s + ls[t + 128]);
    atomicAdd(&stats[128 + f], q + lq[t + 128]);
  }
}

__global__ void bn_apply_relu(float* __restrict__ x, const float* __restrict__ stats,
                              const float* __restrict__ gam, const float* __restrict__ bet,
                              int n, float invn) {
  int idx = blockIdx.x * blockDim.x + threadIdx.x;
  if (idx >= n * 128) return;
  int f = idx & 127;
  float mu = stats[f] * invn;
  float var = stats[128 + f] * invn - mu * mu;
  float sc = rsqrtf(var + 1e-5f) * gam[f];
  float v = (x[idx] - mu) * sc + bet[f];
  x[idx] = fmaxf(v, 0.0f);
}

// ---------------- GEMM: [n,128](f32) @ [128,128] -> [n,128] bf16 ----------------
__global__ __launch_bounds__(256) void gemm128_bf16out(const float* __restrict__ A,
                                                       const float* __restrict__ W,
                                                       unsigned short* __restrict__ C, int n) {
  __shared__ float Ws[64][128];
  __shared__ float As[32][64];
  const int t = threadIdx.x;
  const int tx = t & 31, ty = t >> 5;
  const int row0 = blockIdx.x * 32;
  float acc[4][4] = {{0.f}};
  for (int kk = 0; kk < 128; kk += 64) {
    for (int i = t; i < 2048; i += 256) {
      int r = i >> 5, c4 = (i & 31) << 2;
      *(float4*)&Ws[r][c4] = *(const float4*)&W[(size_t)(kk + r) * 128 + c4];
    }
    for (int i = t; i < 512; i += 256) {
      int r = i >> 4, c4 = (i & 15) << 2;
      int gr = row0 + r;
      float4 v = make_float4(0.f, 0.f, 0.f, 0.f);
      if (gr < n) v = *(const float4*)&A[(size_t)gr * 128 + kk + c4];
      *(float4*)&As[r][c4] = v;
    }
    __syncthreads();
#pragma unroll 8
    for (int k = 0; k < 64; ++k) {
      float4 wv = *(const float4*)&Ws[k][tx << 2];
      float a0 = As[(ty << 2) + 0][k];
      float a1 = As[(ty << 2) + 1][k];
      float a2 = As[(ty << 2) + 2][k];
      float a3 = As[(ty << 2) + 3][k];
      acc[0][0] += a0 * wv.x; acc[0][1] += a0 * wv.y; acc[0][2] += a0 * wv.z; acc[0][3] += a0 * wv.w;
      acc[1][0] += a1 * wv.x; acc[1][1] += a1 * wv.y; acc[1][2] += a1 * wv.z; acc[1][3] += a1 * wv.w;
      acc[2][0] += a2 * wv.x; acc[2][1] += a2 * wv.y; acc[2][2] += a2 * wv.z; acc[2][3] += a2 * wv.w;
      acc[3][0] += a3 * wv.x; acc[3][1] += a3 * wv.y; acc[3][2] += a3 * wv.z; acc[3][3] += a3 * wv.w;
    }
    __syncthreads();
  }
  for (int i = 0; i < 4; ++i) {
    int r = row0 + (ty << 2) + i;
    if (r < n) {
      ushort4 o;
      o.x = f2bf(acc[i][0]); o.y = f2bf(acc[i][1]);
      o.z = f2bf(acc[i][2]); o.w = f2bf(acc[i][3]);
      *(ushort4*)&C[(size_t)r * 128 + (tx << 2)] = o;
    }
  }
}

// ---------------- aggregation over 128 bf16 features (CSR, 32 lanes/node) --------
__global__ __launch_bounds__(256) void agg128_bf16(const unsigned short* __restrict__ h,
                                                   const int* __restrict__ rp,
                                                   const int* __restrict__ csr,
                                                   const float* __restrict__ dinv,
                                                   const float* __restrict__ bias,
                                                   float* __restrict__ out, int n) {
  int node = blockIdx.x * 8 + (threadIdx.x >> 5);
  int lane = threadIdx.x & 31;
  if (node >= n) return;
  float dd = dinv[node];
  float w0 = dd * dd;
  uint2 hv = *(const uint2*)&h[(size_t)node * 128 + lane * 4];
  float ax = bf_lo(hv.x) * w0, ay = bf_hi(hv.x) * w0;
  float az = bf_lo(hv.y) * w0, aw = bf_hi(hv.y) * w0;
  int e0 = rp[node], e1 = rp[node + 1];
  for (int e = e0; e < e1; ++e) {
    int s = csr[e];
    float w = dinv[s] * dd;
    uint2 hs = *(const uint2*)&h[(size_t)s * 128 + lane * 4];
    ax += bf_lo(hs.x) * w; ay += bf_hi(hs.x) * w;
    az += bf_lo(hs.y) * w; aw += bf_hi(hs.y) * w;
  }
  float4 bb = *(const float4*)&bias[lane * 4];
  out[(size_t)node * 128 + lane * 4 + 0] = ax + bb.x;
  out[(size_t)node * 128 + lane * 4 + 1] = ay + bb.y;
  out[(size_t)node * 128 + lane * 4 + 2] = az + bb.z;
  out[(size_t)node * 128 + lane * 4 + 3] = aw + bb.w;
}

// ---------------- pooling ----------------
__global__ void pool_partial(const float* __restrict__ z, const int* __restrict__ gstart,
                             float* __restrict__ pooled) {
  int g = blockIdx.x >> 3, p = blockIdx.x & 7;
  int t = threadIdx.x;
  int f = t & 127, half = t >> 7;
  int beg = gstart[g], end = gstart[g + 1];
  float s = 0.f;
  for (int idx = beg + p * 2 + half; idx < end; idx += 16)
    s += z[(size_t)idx * 128 + f];
  __shared__ float ls[256];
  ls[t] = s;
  __syncthreads();
  if (half == 0) atomicAdd(&pooled[g * 128 + f], s + ls[t + 128]);
}

// ---------------- MLP head + L2 normalize ----------------
__global__ void mlp_kernel(const float* __restrict__ pooled, const int* __restrict__ gstart,
                           const float* __restrict__ Wp1, const float* __restrict__ bp1,
                           const float* __restrict__ Wp2, const float* __restrict__ bp2,
                           float* __restrict__ out) {
  int g = blockIdx.x, t = threadIdx.x;
  __shared__ float pv[128], hid[128], ov[512], red[256];
  if (t < 128) {
    float cntf = (float)(gstart[g + 1] - gstart[g]);
    pv[t] = pooled[g * 128 + t] / fmaxf(cntf, 1.0f);
  }
  __syncthreads();
  if (t < 128) {
    float a = bp1[t];
    for (int k = 0; k < 128; ++k) a += pv[k] * Wp1[k * 128 + t];
    hid[t] = fmaxf(a, 0.0f);
  }
  __syncthreads();
  for (int o = t; o < 512; o += 256) {
    float a = bp2[o];
    for (int k = 0; k < 128; ++k) a += hid[k] * Wp2[k * 512 + o];
    ov[o] = a;
  }
  __syncthreads();
  red[t] = ov[t] * ov[t] + ov[t + 256] * ov[t + 256];
  __syncthreads();
  for (int sdt = 128; sdt > 0; sdt >>= 1) {
    if (t < sdt) red[t] += red[t + sdt];
    __syncthreads();
  }
  float inv = 1.0f / fmaxf(sqrtf(red[0]), 1e-12f);
  for (int o = t; o < 512; o += 256) out[(size_t)g * 512 + o] = ov[o] * inv;
}

// ---------------- host orchestration ----------------
extern "C" void kernel_launch(void* const* d_in, const int* in_sizes, int n_in,
                              void* d_out, int out_size, void* d_ws, size_t ws_size,
                              hipStream_t stream) {
  const int N = in_sizes[0] / 3;
  const int E = in_sizes[1] / 2;
  const int G = out_size / (2 * 512);
  const int NBUCK = (N + BUCKET_MASK) >> BUCKET_SHIFT;

  char* w = (char*)d_ws;
  auto alloc = [&](size_t bytes) -> void* {
    void* p = (void*)w;
    w += (bytes + 255) & ~(size_t)255;
    return p;
  };
  float*          A        = (float*)alloc((size_t)N * 128 * 4);
  unsigned short* Bh       = (unsigned short*)alloc((size_t)N * 128 * 2);
  float*          dinv     = (float*)alloc((size_t)N * 4);
  float*          ag0      = (float*)alloc((size_t)N * 16);
  int*            rp       = (int*)alloc((size_t)(N + 1) * 4);
  int*            csr      = (int*)alloc((size_t)E * 4);
  int2*           bucketed = (int2*)alloc((size_t)E * 8);
  int*            bcnt     = (int*)alloc((size_t)NBUCK * 4);
  int*            bbase    = (int*)alloc((size_t)(NBUCK + 1) * 4);
  int*            bcur     = (int*)alloc((size_t)NBUCK * 4);
  float*          stats    = (float*)alloc(256 * 4);
  int*            gstart   = (int*)alloc((size_t)(G + 1) * 4);
  float*          pooled   = (float*)alloc((size_t)G * 128 * 4);

  const float* W1  = (const float*)d_in[6];
  const float* b1  = (const float*)d_in[7];
  const float* W2  = (const float*)d_in[8];
  const float* b2  = (const float*)d_in[9];
  const float* W3  = (const float*)d_in[10];
  const float* b3  = (const float*)d_in[11];
  const float* g1  = (const float*)d_in[12];
  const float* be1 = (const float*)d_in[13];
  const float* g2  = (const float*)d_in[14];
  const float* be2 = (const float*)d_in[15];
  const float* Wp1 = (const float*)d_in[16];
  const float* bp1 = (const float*)d_in[17];
  const float* Wp2 = (const float*)d_in[18];
  const float* bp2 = (const float*)d_in[19];

  const int TB = 256;
  for (int br = 0; br < 2; ++br) {
    const float* x   = (const float*)d_in[br * 3 + 0];
    const int* ei    = (const int*)d_in[br * 3 + 1];
    const int* src   = ei;
    const int* dst   = ei + E;
    const int* batch = (const int*)d_in[br * 3 + 2];
    float* outp = (float*)d_out + (size_t)br * G * 512;

    // bucketed CSR build (by dst) + degrees + rp
    zero_u32<<<(NBUCK + TB - 1) / TB, TB, 0, stream>>>((unsigned*)bcnt, NBUCK);
    bucket_count<<<256, TB, 0, stream>>>(dst, bcnt, E, NBUCK);
    bucket_scan<<<1, 1024, 0, stream>>>(bcnt, bbase, bcur, NBUCK);
    bucket_scatter<<<(E + TILE - 1) / TILE, TB, 0, stream>>>(src, dst, bcur, bucketed, E, NBUCK);
    bucket_to_csr<<<NBUCK, TB, 0, stream>>>(bucketed, bbase, rp, dinv, csr, N, E, NBUCK);

    // graph boundaries from sorted batch (no atomics)
    graph_bounds<<<(N + TB - 1) / TB, TB, 0, stream>>>(batch, gstart, N, G);

    // layer 1: aggregate x (F=3) then linear -> A
    agg_f3<<<(N + TB - 1) / TB, TB, 0, stream>>>(x, rp, csr, dinv, ag0, N);
    lin_f3<<<(N * 128 + TB - 1) / TB, TB, 0, stream>>>(ag0, W1, b1, A, N);
    zero_u32<<<1, TB, 0, stream>>>((unsigned*)stats, 256);
    bn_stats<<<1024, TB, 0, stream>>>(A, stats, N);
    bn_apply_relu<<<(N * 128 + TB - 1) / TB, TB, 0, stream>>>(A, stats, g1, be1, N, 1.0f / (float)N);

    // layer 2: gemm (bf16 out) -> gather-agg (bf16 in, fp32 out)
    gemm128_bf16out<<<(N + 31) / 32, TB, 0, stream>>>(A, W2, Bh, N);
    agg128_bf16<<<(N + 7) / 8, TB, 0, stream>>>(Bh, rp, csr, dinv, b2, A, N);
    zero_u32<<<1, TB, 0, stream>>>((unsigned*)stats, 256);
    bn_stats<<<1024, TB, 0, stream>>>(A, stats, N);
    bn_apply_relu<<<(N * 128 + TB - 1) / TB, TB, 0, stream>>>(A, stats, g2, be2, N, 1.0f / (float)N);

    // layer 3
    gemm128_bf16out<<<(N + 31) / 32, TB, 0, stream>>>(A, W3, Bh, N);
    agg128_bf16<<<(N + 7) / 8, TB, 0, stream>>>(Bh, rp, csr, dinv, b3, A, N);

    // pool
    zero_u32<<<(G * 128 + TB - 1) / TB, TB, 0, stream>>>((unsigned*)pooled, G * 128);
    pool_partial<<<G * 8, TB, 0, stream>>>(A, gstart, pooled);

    // MLP head + normalize
    mlp_kernel<<<G, TB, 0, stream>>>(pooled, gstart, Wp1, bp1, Wp2, bp2, outp);
  }
}

// Round 5
// 1319.510 us; speedup vs baseline: 1.3200x; 1.3200x over previous
//
#include <hip/hip_runtime.h>
#include <math.h>

#define BUCKET_SHIFT 8            // 256 nodes per bucket
#define BUCKET_MASK 255
#define MAXBUCK 640               // supports N <= 163840
#define TILE 8192

__device__ inline float bf_lo(unsigned u) { return __uint_as_float(u << 16); }
__device__ inline float bf_hi(unsigned u) { return __uint_as_float(u & 0xffff0000u); }
__device__ inline unsigned short f2bf(float f) {   // round-to-nearest-even
  unsigned u = __float_as_uint(f);
  return (unsigned short)((u + 0x7fffu + ((u >> 16) & 1u)) >> 16);
}
__device__ inline void acc8(float* a, uint4 v) {
  a[0] += bf_lo(v.x); a[1] += bf_hi(v.x);
  a[2] += bf_lo(v.y); a[3] += bf_hi(v.y);
  a[4] += bf_lo(v.z); a[5] += bf_hi(v.z);
  a[6] += bf_lo(v.w); a[7] += bf_hi(v.w);
}

// ---------------- utility ----------------
__global__ void zero_u32(unsigned int* __restrict__ p, int n) {
  int i = blockIdx.x * blockDim.x + threadIdx.x;
  if (i < n) p[i] = 0u;
}

// ---------------- bucketed CSR build ----------------
__global__ __launch_bounds__(256) void bucket_count(const int* __restrict__ dst,
                                                    int* __restrict__ bcnt, int e, int nbuck) {
  __shared__ int lc[MAXBUCK];
  for (int i = threadIdx.x; i < nbuck; i += 256) lc[i] = 0;
  __syncthreads();
  for (int i = blockIdx.x * blockDim.x + threadIdx.x; i < e; i += gridDim.x * blockDim.x)
    atomicAdd(&lc[dst[i] >> BUCKET_SHIFT], 1);
  __syncthreads();
  for (int i = threadIdx.x; i < nbuck; i += 256)
    if (lc[i]) atomicAdd(&bcnt[i], lc[i]);
}

__global__ __launch_bounds__(1024) void bucket_scan(const int* __restrict__ bcnt,
                                                    int* __restrict__ bbase,
                                                    int* __restrict__ bcur, int nbuck) {
  __shared__ int s[1024];
  int t = threadIdx.x;
  int v = (t < nbuck) ? bcnt[t] : 0;
  s[t] = v;
  __syncthreads();
  for (int off = 1; off < 1024; off <<= 1) {
    int u = (t >= off) ? s[t - off] : 0;
    __syncthreads();
    s[t] += u;
    __syncthreads();
  }
  int excl = s[t] - v;
  if (t < nbuck) {
    bbase[t] = excl;
    bcur[t] = excl;
  } else if (t == nbuck) {
    bbase[t] = excl;
  }
}

__global__ __launch_bounds__(256) void bucket_scatter(const int* __restrict__ src,
                                                      const int* __restrict__ dst,
                                                      int* __restrict__ bcur,
                                                      int2* __restrict__ bucketed,
                                                      int e, int nbuck) {
  __shared__ int lcnt[MAXBUCK], loff[MAXBUCK], lcur[MAXBUCK], gbase[MAXBUCK];
  __shared__ int stmp[256];
  __shared__ int scarry;
  int t = threadIdx.x;
  int tile0 = blockIdx.x * TILE;
  int tn = min(TILE, e - tile0);
  __shared__ int2 lout[TILE];

  for (int i = t; i < nbuck; i += 256) lcnt[i] = 0;
  if (t == 0) scarry = 0;
  __syncthreads();
  for (int i = t; i < tn; i += 256)
    atomicAdd(&lcnt[dst[tile0 + i] >> BUCKET_SHIFT], 1);
  __syncthreads();
  for (int c0 = 0; c0 < nbuck; c0 += 256) {
    int idx = c0 + t;
    int v = (idx < nbuck) ? lcnt[idx] : 0;
    stmp[t] = v;
    __syncthreads();
    for (int off = 1; off < 256; off <<= 1) {
      int u = (t >= off) ? stmp[t - off] : 0;
      __syncthreads();
      stmp[t] += u;
      __syncthreads();
    }
    int excl = stmp[t] - v + scarry;
    if (idx < nbuck) { loff[idx] = excl; lcur[idx] = excl; }
    __syncthreads();
    if (t == 255) scarry += stmp[255];
    __syncthreads();
  }
  for (int i = t; i < tn; i += 256) {
    int d = dst[tile0 + i];
    int s = src[tile0 + i];
    int b = d >> BUCKET_SHIFT;
    int pos = atomicAdd(&lcur[b], 1);
    lout[pos] = make_int2(s, d);
  }
  __syncthreads();
  for (int i = t; i < nbuck; i += 256)
    if (lcnt[i] > 0) gbase[i] = atomicAdd(&bcur[i], lcnt[i]);
  __syncthreads();
  for (int j = t; j < tn; j += 256) {
    int2 v = lout[j];
    int b = v.y >> BUCKET_SHIFT;
    bucketed[gbase[b] + (j - loff[b])] = v;
  }
}

__global__ __launch_bounds__(256) void bucket_to_csr(const int2* __restrict__ bucketed,
                                                     const int* __restrict__ bbase,
                                                     int* __restrict__ rp,
                                                     float* __restrict__ dinv,
                                                     int* __restrict__ csr,
                                                     int n, int e, int nbuck) {
  __shared__ int lcnt[256], lrp[256];
  int b = blockIdx.x, t = threadIdx.x;
  int n0 = b << BUCKET_SHIFT;
  int base = bbase[b];
  int cnt_e = bbase[b + 1] - base;
  lcnt[t] = 0;
  __syncthreads();
  for (int i = t; i < cnt_e; i += 256)
    atomicAdd(&lcnt[bucketed[base + i].y & BUCKET_MASK], 1);
  __syncthreads();
  int v = lcnt[t];
  lrp[t] = v;
  __syncthreads();
  for (int off = 1; off < 256; off <<= 1) {
    int u = (t >= off) ? lrp[t - off] : 0;
    __syncthreads();
    lrp[t] += u;
    __syncthreads();
  }
  int excl = lrp[t] - v;
  int node = n0 + t;
  if (node < n) {
    rp[node] = base + excl;
    dinv[node] = rsqrtf((float)v + 1.0f);   // +1 self loop
  }
  if (b == nbuck - 1 && t == 0) rp[n] = e;
  lrp[t] = excl;
  lcnt[t] = 0;
  __syncthreads();
  for (int i = t; i < cnt_e; i += 256) {
    int2 ed = bucketed[base + i];
    int li = ed.y & BUCKET_MASK;
    int pos = atomicAdd(&lcnt[li], 1);
    csr[base + lrp[li] + pos] = ed.x;
  }
}

// ---------------- graph boundaries from sorted batch (no atomics) ----------------
__global__ void graph_bounds(const int* __restrict__ batch, int* __restrict__ gstart,
                             int n, int g) {
  int i = blockIdx.x * blockDim.x + threadIdx.x;
  if (i >= n) return;
  int b = batch[i];
  int bp = (i == 0) ? -1 : batch[i - 1];
  for (int k = bp + 1; k <= b; ++k) gstart[k] = i;
  if (i == n - 1)
    for (int k = b + 1; k <= g; ++k) gstart[k] = n;
}

// ---------------- layer 1: pre-scale x by dinv, aggregate, then linear ----------
__global__ void xs_scale(const float* __restrict__ x, const float* __restrict__ dinv,
                         float4* __restrict__ xs, int n) {
  int i = blockIdx.x * blockDim.x + threadIdx.x;
  if (i >= n) return;
  float d = dinv[i];
  xs[i] = make_float4(x[3 * (size_t)i] * d, x[3 * (size_t)i + 1] * d,
                      x[3 * (size_t)i + 2] * d, d);
}

__global__ void agg_f3(const float4* __restrict__ xs, const int* __restrict__ rp,
                       const int* __restrict__ csr, const float* __restrict__ dinv,
                       float* __restrict__ out, int n) {
  int i = blockIdx.x * blockDim.x + threadIdx.x;
  if (i >= n) return;
  float4 self = xs[i];
  float a0 = self.x, a1 = self.y, a2 = self.z;
  int e0 = rp[i], e1 = rp[i + 1];
  int e = e0;
  for (; e + 4 <= e1; e += 4) {
    int s0 = csr[e], s1 = csr[e + 1], s2 = csr[e + 2], s3 = csr[e + 3];
    float4 v0 = xs[s0], v1 = xs[s1], v2 = xs[s2], v3 = xs[s3];
    a0 += (v0.x + v1.x) + (v2.x + v3.x);
    a1 += (v0.y + v1.y) + (v2.y + v3.y);
    a2 += (v0.z + v1.z) + (v2.z + v3.z);
  }
  for (; e < e1; ++e) {
    float4 v = xs[csr[e]];
    a0 += v.x; a1 += v.y; a2 += v.z;
  }
  float d = dinv[i];
  out[4 * (size_t)i + 0] = a0 * d;
  out[4 * (size_t)i + 1] = a1 * d;
  out[4 * (size_t)i + 2] = a2 * d;
}

__global__ void lin_f3(const float* __restrict__ ag, const float* __restrict__ W1,
                       const float* __restrict__ b1, float* __restrict__ out, int n) {
  int idx = blockIdx.x * blockDim.x + threadIdx.x;
  if (idx >= n * 128) return;
  int node = idx >> 7, f = idx & 127;
  float a = b1[f]
          + ag[4 * (size_t)node + 0] * W1[f]
          + ag[4 * (size_t)node + 1] * W1[128 + f]
          + ag[4 * (size_t)node + 2] * W1[256 + f];
  out[idx] = a;
}

// ---------------- batch norm ----------------
__global__ void bn_stats(const float* __restrict__ x, float* __restrict__ stats, int n) {
  int t = threadIdx.x;
  int f = t & 127, half = t >> 7;
  float s = 0.f, q = 0.f;
  for (int r = blockIdx.x * 2 + half; r < n; r += gridDim.x * 2) {
    float v = x[(size_t)r * 128 + f];
    s += v;
    q += v * v;
  }
  __shared__ float ls[256], lq[256];
  ls[t] = s; lq[t] = q;
  __syncthreads();
  if (half == 0) {
    atomicAdd(&stats[f], s + ls[t + 128]);
    atomicAdd(&stats[128 + f], q + lq[t + 128]);
  }
}

__global__ void bn_apply_relu(float* __restrict__ x, const float* __restrict__ stats,
                              const float* __restrict__ gam, const float* __restrict__ bet,
                              int n, float invn) {
  int idx = blockIdx.x * blockDim.x + threadIdx.x;
  if (idx >= n * 128) return;
  int f = idx & 127;
  float mu = stats[f] * invn;
  float var = stats[128 + f] * invn - mu * mu;
  float sc = rsqrtf(var + 1e-5f) * gam[f];
  float v = (x[idx] - mu) * sc + bet[f];
  x[idx] = fmaxf(v, 0.0f);
}

// -------- GEMM: [n,128](f32) @ [128,128], epilogue scales row by dinv, bf16 out --
__global__ __launch_bounds__(256) void gemm128_bf16out(const float* __restrict__ A,
                                                       const float* __restrict__ W,
                                                       const float* __restrict__ dinv,
                                                       unsigned short* __restrict__ C, int n) {
  __shared__ float Ws[64][128];
  __shared__ float As[32][64];
  const int t = threadIdx.x;
  const int tx = t & 31, ty = t >> 5;
  const int row0 = blockIdx.x * 32;
  float acc[4][4] = {{0.f}};
  for (int kk = 0; kk < 128; kk += 64) {
    for (int i = t; i < 2048; i += 256) {
      int r = i >> 5, c4 = (i & 31) << 2;
      *(float4*)&Ws[r][c4] = *(const float4*)&W[(size_t)(kk + r) * 128 + c4];
    }
    for (int i = t; i < 512; i += 256) {
      int r = i >> 4, c4 = (i & 15) << 2;
      int gr = row0 + r;
      float4 v = make_float4(0.f, 0.f, 0.f, 0.f);
      if (gr < n) v = *(const float4*)&A[(size_t)gr * 128 + kk + c4];
      *(float4*)&As[r][c4] = v;
    }
    __syncthreads();
#pragma unroll 8
    for (int k = 0; k < 64; ++k) {
      float4 wv = *(const float4*)&Ws[k][tx << 2];
      float a0 = As[(ty << 2) + 0][k];
      float a1 = As[(ty << 2) + 1][k];
      float a2 = As[(ty << 2) + 2][k];
      float a3 = As[(ty << 2) + 3][k];
      acc[0][0] += a0 * wv.x; acc[0][1] += a0 * wv.y; acc[0][2] += a0 * wv.z; acc[0][3] += a0 * wv.w;
      acc[1][0] += a1 * wv.x; acc[1][1] += a1 * wv.y; acc[1][2] += a1 * wv.z; acc[1][3] += a1 * wv.w;
      acc[2][0] += a2 * wv.x; acc[2][1] += a2 * wv.y; acc[2][2] += a2 * wv.z; acc[2][3] += a2 * wv.w;
      acc[3][0] += a3 * wv.x; acc[3][1] += a3 * wv.y; acc[3][2] += a3 * wv.z; acc[3][3] += a3 * wv.w;
    }
    __syncthreads();
  }
  for (int i = 0; i < 4; ++i) {
    int r = row0 + (ty << 2) + i;
    if (r < n) {
      float sc = dinv[r];
      ushort4 o;
      o.x = f2bf(acc[i][0] * sc); o.y = f2bf(acc[i][1] * sc);
      o.z = f2bf(acc[i][2] * sc); o.w = f2bf(acc[i][3] * sc);
      *(ushort4*)&C[(size_t)r * 128 + (tx << 2)] = o;
    }
  }
}

// ------- aggregation of pre-scaled bf16 rows: 16 lanes/node, 8 bf16/lane --------
__global__ __launch_bounds__(256) void agg128_bf16(const unsigned short* __restrict__ h,
                                                   const int* __restrict__ rp,
                                                   const int* __restrict__ csr,
                                                   const float* __restrict__ dinv,
                                                   const float* __restrict__ bias,
                                                   float* __restrict__ out, int n) {
  int node = blockIdx.x * 16 + (threadIdx.x >> 4);
  int lane = threadIdx.x & 15;
  if (node >= n) return;
  const uint4* hp = (const uint4*)h;             // row = 16 uint4 (256 B)
  float acc[8] = {0.f};
  acc8(acc, hp[(size_t)node * 16 + lane]);       // self term (pre-scaled)
  int e0 = rp[node], e1 = rp[node + 1];
  int e = e0;
  for (; e + 4 <= e1; e += 4) {
    int s0 = csr[e], s1 = csr[e + 1], s2 = csr[e + 2], s3 = csr[e + 3];
    uint4 v0 = hp[(size_t)s0 * 16 + lane];
    uint4 v1 = hp[(size_t)s1 * 16 + lane];
    uint4 v2 = hp[(size_t)s2 * 16 + lane];
    uint4 v3 = hp[(size_t)s3 * 16 + lane];
    acc8(acc, v0); acc8(acc, v1); acc8(acc, v2); acc8(acc, v3);
  }
  for (; e < e1; ++e) acc8(acc, hp[(size_t)csr[e] * 16 + lane]);
  float dd = dinv[node];
  float4 bb0 = *(const float4*)&bias[lane * 8];
  float4 bb1 = *(const float4*)&bias[lane * 8 + 4];
  float4 o0 = make_float4(acc[0] * dd + bb0.x, acc[1] * dd + bb0.y,
                          acc[2] * dd + bb0.z, acc[3] * dd + bb0.w);
  float4 o1 = make_float4(acc[4] * dd + bb1.x, acc[5] * dd + bb1.y,
                          acc[6] * dd + bb1.z, acc[7] * dd + bb1.w);
  *(float4*)&out[(size_t)node * 128 + lane * 8] = o0;
  *(float4*)&out[(size_t)node * 128 + lane * 8 + 4] = o1;
}

// ---------------- pooling ----------------
__global__ void pool_partial(const float* __restrict__ z, const int* __restrict__ gstart,
                             float* __restrict__ pooled) {
  int g = blockIdx.x >> 3, p = blockIdx.x & 7;
  int t = threadIdx.x;
  int f = t & 127, half = t >> 7;
  int beg = gstart[g], end = gstart[g + 1];
  float s = 0.f;
  for (int idx = beg + p * 2 + half; idx < end; idx += 16)
    s += z[(size_t)idx * 128 + f];
  __shared__ float ls[256];
  ls[t] = s;
  __syncthreads();
  if (half == 0) atomicAdd(&pooled[g * 128 + f], s + ls[t + 128]);
}

// ---------------- MLP head + L2 normalize ----------------
__global__ void mlp_kernel(const float* __restrict__ pooled, const int* __restrict__ gstart,
                           const float* __restrict__ Wp1, const float* __restrict__ bp1,
                           const float* __restrict__ Wp2, const float* __restrict__ bp2,
                           float* __restrict__ out) {
  int g = blockIdx.x, t = threadIdx.x;
  __shared__ float pv[128], hid[128], ov[512], red[256];
  if (t < 128) {
    float cntf = (float)(gstart[g + 1] - gstart[g]);
    pv[t] = pooled[g * 128 + t] / fmaxf(cntf, 1.0f);
  }
  __syncthreads();
  if (t < 128) {
    float a = bp1[t];
    for (int k = 0; k < 128; ++k) a += pv[k] * Wp1[k * 128 + t];
    hid[t] = fmaxf(a, 0.0f);
  }
  __syncthreads();
  for (int o = t; o < 512; o += 256) {
    float a = bp2[o];
    for (int k = 0; k < 128; ++k) a += hid[k] * Wp2[k * 512 + o];
    ov[o] = a;
  }
  __syncthreads();
  red[t] = ov[t] * ov[t] + ov[t + 256] * ov[t + 256];
  __syncthreads();
  for (int sdt = 128; sdt > 0; sdt >>= 1) {
    if (t < sdt) red[t] += red[t + sdt];
    __syncthreads();
  }
  float inv = 1.0f / fmaxf(sqrtf(red[0]), 1e-12f);
  for (int o = t; o < 512; o += 256) out[(size_t)g * 512 + o] = ov[o] * inv;
}

// ---------------- host orchestration ----------------
extern "C" void kernel_launch(void* const* d_in, const int* in_sizes, int n_in,
                              void* d_out, int out_size, void* d_ws, size_t ws_size,
                              hipStream_t stream) {
  const int N = in_sizes[0] / 3;
  const int E = in_sizes[1] / 2;
  const int G = out_size / (2 * 512);
  const int NBUCK = (N + BUCKET_MASK) >> BUCKET_SHIFT;

  char* w = (char*)d_ws;
  auto alloc = [&](size_t bytes) -> void* {
    void* p = (void*)w;
    w += (bytes + 255) & ~(size_t)255;
    return p;
  };
  float*          A        = (float*)alloc((size_t)N * 128 * 4);
  unsigned short* Bh       = (unsigned short*)alloc((size_t)N * 128 * 2);
  float*          dinv     = (float*)alloc((size_t)N * 4);
  float4*         xs       = (float4*)alloc((size_t)N * 16);
  float*          ag0      = (float*)alloc((size_t)N * 16);
  int*            rp       = (int*)alloc((size_t)(N + 1) * 4);
  int*            csr      = (int*)alloc((size_t)E * 4);
  int2*           bucketed = (int2*)alloc((size_t)E * 8);
  int*            bcnt     = (int*)alloc((size_t)NBUCK * 4);
  int*            bbase    = (int*)alloc((size_t)(NBUCK + 1) * 4);
  int*            bcur     = (int*)alloc((size_t)NBUCK * 4);
  float*          stats    = (float*)alloc(256 * 4);
  int*            gstart   = (int*)alloc((size_t)(G + 1) * 4);
  float*          pooled   = (float*)alloc((size_t)G * 128 * 4);

  const float* W1  = (const float*)d_in[6];
  const float* b1  = (const float*)d_in[7];
  const float* W2  = (const float*)d_in[8];
  const float* b2  = (const float*)d_in[9];
  const float* W3  = (const float*)d_in[10];
  const float* b3  = (const float*)d_in[11];
  const float* g1  = (const float*)d_in[12];
  const float* be1 = (const float*)d_in[13];
  const float* g2  = (const float*)d_in[14];
  const float* be2 = (const float*)d_in[15];
  const float* Wp1 = (const float*)d_in[16];
  const float* bp1 = (const float*)d_in[17];
  const float* Wp2 = (const float*)d_in[18];
  const float* bp2 = (const float*)d_in[19];

  const int TB = 256;
  for (int br = 0; br < 2; ++br) {
    const float* x   = (const float*)d_in[br * 3 + 0];
    const int* ei    = (const int*)d_in[br * 3 + 1];
    const int* src   = ei;
    const int* dst   = ei + E;
    const int* batch = (const int*)d_in[br * 3 + 2];
    float* outp = (float*)d_out + (size_t)br * G * 512;

    // bucketed CSR build (by dst) + degrees + rp
    zero_u32<<<(NBUCK + TB - 1) / TB, TB, 0, stream>>>((unsigned*)bcnt, NBUCK);
    bucket_count<<<256, TB, 0, stream>>>(dst, bcnt, E, NBUCK);
    bucket_scan<<<1, 1024, 0, stream>>>(bcnt, bbase, bcur, NBUCK);
    bucket_scatter<<<(E + TILE - 1) / TILE, TB, 0, stream>>>(src, dst, bcur, bucketed, E, NBUCK);
    bucket_to_csr<<<NBUCK, TB, 0, stream>>>(bucketed, bbase, rp, dinv, csr, N, E, NBUCK);

    // graph boundaries from sorted batch (no atomics)
    graph_bounds<<<(N + TB - 1) / TB, TB, 0, stream>>>(batch, gstart, N, G);

    // layer 1: pre-scale x, aggregate (pre-scaled), linear -> A
    xs_scale<<<(N + TB - 1) / TB, TB, 0, stream>>>(x, dinv, xs, N);
    agg_f3<<<(N + TB - 1) / TB, TB, 0, stream>>>(xs, rp, csr, dinv, ag0, N);
    lin_f3<<<(N * 128 + TB - 1) / TB, TB, 0, stream>>>(ag0, W1, b1, A, N);
    zero_u32<<<1, TB, 0, stream>>>((unsigned*)stats, 256);
    bn_stats<<<1024, TB, 0, stream>>>(A, stats, N);
    bn_apply_relu<<<(N * 128 + TB - 1) / TB, TB, 0, stream>>>(A, stats, g1, be1, N, 1.0f / (float)N);

    // layer 2: gemm (dinv-scaled bf16 out) -> sum-agg -> final dinv scale
    gemm128_bf16out<<<(N + 31) / 32, TB, 0, stream>>>(A, W2, dinv, Bh, N);
    agg128_bf16<<<(N + 15) / 16, TB, 0, stream>>>(Bh, rp, csr, dinv, b2, A, N);
    zero_u32<<<1, TB, 0, stream>>>((unsigned*)stats, 256);
    bn_stats<<<1024, TB, 0, stream>>>(A, stats, N);
    bn_apply_relu<<<(N * 128 + TB - 1) / TB, TB, 0, stream>>>(A, stats, g2, be2, N, 1.0f / (float)N);

    // layer 3
    gemm128_bf16out<<<(N + 31) / 32, TB, 0, stream>>>(A, W3, dinv, Bh, N);
    agg128_bf16<<<(N + 15) / 16, TB, 0, stream>>>(Bh, rp, csr, dinv, b3, A, N);

    // pool
    zero_u32<<<(G * 128 + TB - 1) / TB, TB, 0, stream>>>((unsigned*)pooled, G * 128);
    pool_partial<<<G * 8, TB, 0, stream>>>(A, gstart, pooled);

    // MLP head + normalize
    mlp_kernel<<<G, TB, 0, stream>>>(pooled, gstart, Wp1, bp1, Wp2, bp2, outp);
  }
}